// Round 9
// baseline (446.410 us; speedup 1.0000x reference)
//
#include <hip/hip_runtime.h>
#include <hip/hip_fp16.h>

// Hankel MPS, round 14: r-split pairs (halve per-CU L2 traffic) + coalesced prep.
//
// Round-13 post-mortem: depth-2+rotation changed nothing (284us both) ->
// hard ceiling = L2 fabric: 64 MB/XCD/step at ~2.25 TB/s/XCD. Only fix:
// fewer H bytes per CU.
//
// Round-14:
//  - chain: 256 blocks = 128 b-tiles (64 b) x 2 r-half roles. Block computes
//    its 32 output rows over ALL 128 e -> per-CU H = 1 MB/step (L2 floor
//    13.3us/step ~ MFMA floor 10.3). Pair exchanges v-halves per step:
//    pure concat via sc1 vbuf (8KB each way) + pairwise monotonic flag
//    (base+t protocol: no resets, replay-safe; 256 blocks <= capacity ->
//    both resident -> deadlock-free).
//  - prep: H conversion was scatter-read (32KB p-stride, ~16x overfetch).
//    Now: block per (t,e) slice; coalesced f32 reads -> LDS fragment
//    scatter -> coalesced 16B writes.
//
// ws: encH 25.17M | HmH 10.49M | HmL 10.49M | w1f 64K | w2f 128K |
//     vbuf 4M @46333952  (50.5 MB total)

#define B_ALL 8192
#define TT    12

typedef short bfrag __attribute__((ext_vector_type(8)));      // 8 bf16
typedef _Float16 hfrag __attribute__((ext_vector_type(8)));   // 8 fp16
typedef float ffrag __attribute__((ext_vector_type(16)));     // 32x32 C/D

#define O_ENC   0ULL
#define O_HMH   25165824ULL
#define O_HML   35651584ULL
#define O_W1F   46137344ULL
#define O_W2F   46202880ULL
#define O_VBUF  46333952ULL            // 128 pairs x 2 parity x 2 half x 8KB

__device__ __forceinline__ unsigned short bf16_rne(float f) {
    unsigned int u = __builtin_bit_cast(unsigned int, f);
    unsigned int r = (u + 0x7fffu + ((u >> 16) & 1u)) >> 16;
    return (unsigned short)r;
}
__device__ __forceinline__ float bf16_f32(unsigned short h) {
    unsigned int u = ((unsigned int)h) << 16;
    return __builtin_bit_cast(float, u);
}

// sc1 (device-coherent) accessors
__device__ __forceinline__ void st_f1_sc1(float* p, float v) {
    __hip_atomic_store(p, v, __ATOMIC_RELAXED, __HIP_MEMORY_SCOPE_AGENT);
}
__device__ __forceinline__ float2 ld_f2_sc1(const float* p) {
    unsigned long long u = __hip_atomic_load((unsigned long long*)(size_t)p,
                                             __ATOMIC_RELAXED,
                                             __HIP_MEMORY_SCOPE_AGENT);
    return __builtin_bit_cast(float2, u);
}

// ---------------- prep: coalesced H conversion + W frag-order ----------------
// grid 1288: blocks 0..1279 = one (t,e) H slice each; 1280..1287 = W1/W2.
__global__ __launch_bounds__(256)
void prep_kernel(const float* __restrict__ W1, const float* __restrict__ W2,
                 const float* __restrict__ Hm,
                 __half* __restrict__ w1f, __half* __restrict__ w2f,
                 unsigned short* __restrict__ Hh, unsigned short* __restrict__ Hl)
{
    const int tid = threadIdx.x;
    const int bid = blockIdx.x;
    if (bid < 1280) {
        // one 64p x 64r slice: coalesced read, LDS fragment scatter, coalesced write
        __shared__ unsigned short hs[4096], ls[4096];
        const int t = bid >> 7, e = bid & 127;
        const float* src = Hm + ((size_t)t * 64 * 128 + e) * 64;   // + p*8192 + r
        const int p  = tid >> 2;
        const int rc = (tid & 3) * 16;
        const int fp = (p >> 4) * 512 + ((p >> 3) & 1) * 256 + (p & 7); // p part of f
        #pragma unroll
        for (int k4 = 0; k4 < 4; ++k4) {
            const int r0 = rc + k4 * 4;
            const float4 v4 = *(const float4*)&src[(size_t)p * 8192 + r0];
            const float vv[4] = {v4.x, v4.y, v4.z, v4.w};
            #pragma unroll
            for (int k = 0; k < 4; ++k) {
                const int r = r0 + k;
                const int f = (r >> 5) * 2048 + (r & 31) * 8 + fp;
                const float val = vv[k];
                const unsigned short hi = bf16_rne(val);
                const unsigned short lo = bf16_rne(val - bf16_f32(hi));
                hs[f] = hi;
                ls[f] = lo;
            }
        }
        __syncthreads();
        const size_t q0 = (size_t)t * 524288 + (size_t)e * 4096 + tid * 16;
        *(uint4*)&Hh[q0]     = *(const uint4*)&hs[tid * 16];
        *(uint4*)&Hh[q0 + 8] = *(const uint4*)&hs[tid * 16 + 8];
        *(uint4*)&Hl[q0]     = *(const uint4*)&ls[tid * 16];
        *(uint4*)&Hl[q0 + 8] = *(const uint4*)&ls[tid * 16 + 8];
    } else {
        const int wb = bid - 1280;
        const long long N_W1 = 32768, N_W2 = 65536;
        for (long long idx = wb * 256 + tid; idx < N_W1 + N_W2; idx += 8 * 256) {
            if (idx < N_W1) {
                const int w = (int)idx;
                const int jn = w >> 11, ks = (w >> 9) & 3, half = (w >> 8) & 1;
                const int jl = (w >> 3) & 31, jj = w & 7;
                const int j = jn * 32 + jl, d = ks * 16 + half * 8 + jj;
                w1f[w] = __float2half(W1[j * 64 + d]);
            } else {
                const int w = (int)(idx - N_W1);
                const int en = w >> 14, ks2g = (w >> 9) & 31, half = (w >> 8) & 1;
                const int el = (w >> 3) & 31, jj = w & 7;
                const int e = en * 32 + el, j = ks2g * 16 + half * 8 + jj;
                w2f[w] = __float2half(W2[e * 512 + j]);
            }
        }
    }
}

// ---------------- encoder (unchanged) ----------------
__global__ __launch_bounds__(256)
void enc_kernel(const float* __restrict__ x,
                const float* __restrict__ b1, const float* __restrict__ b2,
                const __half* __restrict__ w1f, const __half* __restrict__ w2f,
                __half* __restrict__ encH)
{
    __shared__ __align__(16) unsigned char smem[17408];
    float* x_s  = (float*)smem;
    __half* h_s = (__half*)smem;

    const int tid   = threadIdx.x;
    const int wv    = tid >> 6;
    const int lane  = tid & 63;
    const int l32   = lane & 31;
    const int half  = lane >> 5;
    const int msub  = wv >> 1;
    const int nhalf = wv & 1;
    const int m0    = blockIdx.x * 64;

    #pragma unroll
    for (int i = 0; i < 4; ++i) {
        const int f4 = i * 256 + tid;
        const int r = f4 >> 4, c4 = (f4 & 15) * 4;
        *(float4*)&x_s[r * 68 + c4] =
            *(const float4*)&x[(long long)(m0 + r) * 64 + c4];
    }
    __syncthreads();

    hfrag xa[4];
    #pragma unroll
    for (int ks = 0; ks < 4; ++ks) {
        const float* src = &x_s[(msub * 32 + l32) * 68 + ks * 16 + half * 8];
        const float4 a = *(const float4*)src;
        const float4 b = *(const float4*)(src + 4);
        hfrag v;
        v[0] = (_Float16)a.x; v[1] = (_Float16)a.y;
        v[2] = (_Float16)a.z; v[3] = (_Float16)a.w;
        v[4] = (_Float16)b.x; v[5] = (_Float16)b.y;
        v[6] = (_Float16)b.z; v[7] = (_Float16)b.w;
        xa[ks] = v;
    }
    __syncthreads();

    ffrag c2[2];
    c2[0] = 0.0f; c2[1] = 0.0f;

    for (int chunk = 0; chunk < 4; ++chunk) {
        ffrag c1[2];
        float b1j[2];
        #pragma unroll
        for (int nf = 0; nf < 2; ++nf) {
            const int jn = chunk * 4 + nhalf * 2 + nf;
            b1j[nf] = b1[jn * 32 + l32];
            ffrag acc = 0.0f;
            #pragma unroll
            for (int ks = 0; ks < 4; ++ks) {
                const hfrag bh = *(const hfrag*)(w1f + (jn * 4 + ks) * 512
                                                 + half * 256 + l32 * 8);
                acc = __builtin_amdgcn_mfma_f32_32x32x16_f16(xa[ks], bh, acc, 0, 0, 0);
            }
            c1[nf] = acc;
        }
        __syncthreads();
        #pragma unroll
        for (int nf = 0; nf < 2; ++nf) {
            #pragma unroll
            for (int i2 = 0; i2 < 16; ++i2) {
                const int m_row = (i2 & 3) + 8 * (i2 >> 2) + 4 * half;
                const float v = fmaxf(c1[nf][i2] + b1j[nf], 0.0f);
                h_s[(msub * 32 + m_row) * 136 + nhalf * 64 + nf * 32 + l32] =
                    __float2half(v);
            }
        }
        __syncthreads();
        #pragma unroll
        for (int ks2 = 0; ks2 < 8; ++ks2) {
            const hfrag a = *(const hfrag*)&h_s[(msub * 32 + l32) * 136
                                                + ks2 * 16 + half * 8];
            const int ks2g = chunk * 8 + ks2;
            #pragma unroll
            for (int ef = 0; ef < 2; ++ef) {
                const int en = nhalf * 2 + ef;
                const hfrag b = *(const hfrag*)(w2f + (en * 32 + ks2g) * 512
                                                + half * 256 + l32 * 8);
                c2[ef] = __builtin_amdgcn_mfma_f32_32x32x16_f16(a, b, c2[ef], 0, 0, 0);
            }
        }
    }

    #pragma unroll
    for (int ef = 0; ef < 2; ++ef) {
        const int e = nhalf * 64 + ef * 32 + l32;
        const float b2e = b2[e];
        #pragma unroll
        for (int i2 = 0; i2 < 16; ++i2) {
            const int m_row = (i2 & 3) + 8 * (i2 >> 2) + 4 * half;
            const int m_g = m0 + msub * 32 + m_row;
            encH[(long long)m_g * 128 + e] =
                __float2half(fmaxf(c2[ef][i2] + b2e, 0.0f));
        }
    }
}

// ---------------- chain: r-split pairs ----------------
// 256 blocks x 512 thr. pid = bid>>1 (b-tile, 64 b), rr = bid&1 (r-half).
// Block computes rows rr*32..rr*32+31 over ALL 128 e; pair exchanges
// v-halves per step via sc1 vbuf + monotonic flag (base+t).
//
// Waves: eq = wv>>1 (32-e quarter), bh = wv&1 (b-half).
// LDS (52800 B):
//   vsum  @ 0     : [64 p][66] f32 = 16896
//   enc_s @ 16896 : [128 e][66] f32 = 33792  (eq-combine scratch aliases this)
//   red   @ 50688 : [8][66] f32 = 2112       (final)
__device__ unsigned int g_flag[256 * 32];   // per block, 128-B padded

__global__ __launch_bounds__(512, 1)
void chain_all(const unsigned short* __restrict__ HmH,
               const unsigned short* __restrict__ HmL,
               const __half* __restrict__ encH,
               const float* __restrict__ Hf,
               const float* __restrict__ HL,
               float* vbuf,
               float* __restrict__ out)
{
    __shared__ __align__(16) unsigned char smem[52800];
    float* vsum  = (float*)smem;
    float* enc_s = (float*)(smem + 16896);
    float* red   = (float*)(smem + 50688);

    const int tid  = threadIdx.x;
    const int bid  = blockIdx.x;
    const int pid  = bid >> 1;
    const int rr   = bid & 1;
    const int b0   = pid * 64;
    const int lane = tid & 63;
    const int wv   = tid >> 6;
    const int l32  = lane & 31;
    const int half = lane >> 5;
    const int eq   = wv >> 1;      // 0..3
    const int bh   = wv & 1;       // 0..1
    const int bcol = bh * 32 + l32;

    unsigned int fbase = 0;
    if (tid == 0)
        fbase = __hip_atomic_load(&g_flag[bid * 32], __ATOMIC_RELAXED,
                                  __HIP_MEMORY_SCOPE_AGENT);

    // enc staging: [128 e][64 b] for one timestep
    const int sbL = tid >> 3;            // 0..63 (b-local)
    const int seo = (tid & 7) * 16;      // 0..112 (e-offset)
    #define STAGE_ENC(T)                                                        \
    {                                                                           \
        const __half* er_ = encH + ((size_t)(b0 + sbL) * 12 + (T)) * 128 + seo; \
        uint4 u0_ = *(const uint4*)er_;                                         \
        uint4 u1_ = *(const uint4*)(er_ + 8);                                   \
        const __half* hp_ = (const __half*)&u0_;                                \
        const __half* hq_ = (const __half*)&u1_;                                \
        _Pragma("unroll")                                                       \
        for (int j = 0; j < 8; ++j)                                             \
            enc_s[(seo + j) * 66 + sbL] = __half2float(hp_[j]);                 \
        _Pragma("unroll")                                                       \
        for (int j = 0; j < 8; ++j)                                             \
            enc_s[(seo + 8 + j) * 66 + sbL] = __half2float(hq_[j]);             \
    }

    // ---- init: full v0 (both blocks of pair compute it; no exchange) ----
    {
        STAGE_ENC(0);
        __syncthreads();
        const int pg = tid >> 6, bI = tid & 63;   // pg 0..7
        float acc[8] = {0, 0, 0, 0, 0, 0, 0, 0};
        for (int e = 0; e < 128; ++e) {
            const float ev = enc_s[e * 66 + bI];
            const float4 h0 = *(const float4*)&Hf[e * 64 + pg * 8];     // wave-uniform
            const float4 h1 = *(const float4*)&Hf[e * 64 + pg * 8 + 4];
            acc[0] += ev * h0.x; acc[1] += ev * h0.y;
            acc[2] += ev * h0.z; acc[3] += ev * h0.w;
            acc[4] += ev * h1.x; acc[5] += ev * h1.y;
            acc[6] += ev * h1.z; acc[7] += ev * h1.w;
        }
        #pragma unroll
        for (int i = 0; i < 8; ++i)
            vsum[(pg * 8 + i) * 66 + bI] = acc[i];
        __syncthreads();
    }

    // ---- chain: 10 steps ----
    const unsigned short* Hsh = HmH;
    const unsigned short* Hsl = HmL;
    const int lanoff = rr * 2048 + half * 256 + l32 * 8;   // r-half is block role

    #pragma unroll 1
    for (int t = 1; t <= 10; ++t) {
        STAGE_ENC(t);

        // B-frags: full-p v hi/lo split for this wave's 32-b columns
        bfrag vbh_[4], vbl_[4];
        #pragma unroll
        for (int s = 0; s < 4; ++s) {
            const int p0 = s * 16 + half * 8;
            bfrag hb, lb;
            #pragma unroll
            for (int j = 0; j < 8; ++j) {
                const float f = vsum[(p0 + j) * 66 + bcol];
                const unsigned short hi = bf16_rne(f);
                const unsigned short lo = bf16_rne(f - bf16_f32(hi));
                hb[j] = (short)hi;
                lb[j] = (short)lo;
            }
            vbh_[s] = hb;
            vbl_[s] = lb;
        }
        __syncthreads();   // enc_s staged; vsum reads complete

        // e-loop: 32-e quarter, depth-1 ping-pong prefetch
        const unsigned short* hp = Hsh + (size_t)(eq * 32) * 4096 + lanoff;
        const unsigned short* lp = Hsl + (size_t)(eq * 32) * 4096 + lanoff;
        bfrag cah[4], cal[4];
        #pragma unroll
        for (int s = 0; s < 4; ++s) {
            cah[s] = *(const bfrag*)(hp + s * 512);
            cal[s] = *(const bfrag*)(lp + s * 512);
        }
        ffrag z = 0.0f;
        ffrag vn = 0.0f;
        #pragma unroll 2
        for (int e = 0; e < 32; ++e) {
            hp += 4096; lp += 4096;
            bfrag nah[4], nal[4];   // last iter reads <=8KB past slice (allocated)
            #pragma unroll
            for (int s = 0; s < 4; ++s) {
                nah[s] = *(const bfrag*)(hp + s * 512);
                nal[s] = *(const bfrag*)(lp + s * 512);
            }
            const float ev = enc_s[(eq * 32 + e) * 66 + bcol];
            ffrag w = z;
            #pragma unroll
            for (int s = 0; s < 4; ++s) {
                w = __builtin_amdgcn_mfma_f32_32x32x16_bf16(cah[s], vbh_[s], w, 0, 0, 0);
                w = __builtin_amdgcn_mfma_f32_32x32x16_bf16(cah[s], vbl_[s], w, 0, 0, 0);
                w = __builtin_amdgcn_mfma_f32_32x32x16_bf16(cal[s], vbh_[s], w, 0, 0, 0);
            }
            vn += w * ev;
            #pragma unroll
            for (int s = 0; s < 4; ++s) { cah[s] = nah[s]; cal[s] = nal[s]; }
        }
        __syncthreads();   // e-loop LDS reads done; enc_s region reusable

        // cross-eq combine (scratch aliases enc_s)
        float4* sc4 = (float4*)enc_s;
        if (eq != 0) {
            const int slot = (eq - 1) * 2 + bh;
            #pragma unroll
            for (int q = 0; q < 4; ++q) {
                float4 f4 = {vn[q * 4 + 0], vn[q * 4 + 1],
                             vn[q * 4 + 2], vn[q * 4 + 3]};
                sc4[(slot * 4 + q) * 66 + lane] = f4;
            }
        }
        __syncthreads();
        if (eq == 0) {
            #pragma unroll
            for (int g = 1; g < 4; ++g) {
                const int slot = (g - 1) * 2 + bh;
                #pragma unroll
                for (int q = 0; q < 4; ++q) {
                    const float4 f4 = sc4[(slot * 4 + q) * 66 + lane];
                    vn[q * 4 + 0] += f4.x; vn[q * 4 + 1] += f4.y;
                    vn[q * 4 + 2] += f4.z; vn[q * 4 + 3] += f4.w;
                }
            }
            // own half -> vsum (LDS) and vbuf (sc1 for partner)
            float* vb = vbuf + (((size_t)pid * 2 + (t & 1)) * 2 + rr) * 2048;
            #pragma unroll
            for (int i = 0; i < 16; ++i) {
                const int roffs = (i & 3) + 8 * (i >> 2) + 4 * half;
                vsum[(rr * 32 + roffs) * 66 + bcol] = vn[i];
                st_f1_sc1(&vb[roffs * 64 + bcol], vn[i]);
            }
        }
        __syncthreads();   // drain all stores (vmcnt 0 at barrier)

        if (tid == 0) {
            __hip_atomic_store(&g_flag[bid * 32], fbase + t, __ATOMIC_RELAXED,
                               __HIP_MEMORY_SCOPE_AGENT);
            while (__hip_atomic_load(&g_flag[(bid ^ 1) * 32], __ATOMIC_RELAXED,
                                     __HIP_MEMORY_SCOPE_AGENT) < fbase + t)
                __builtin_amdgcn_s_sleep(8);
        }
        __syncthreads();   // partner data at MALL

        // copy partner half into vsum
        {
            const float* pb = vbuf + (((size_t)pid * 2 + (t & 1)) * 2 + (rr ^ 1)) * 2048;
            const int i4 = tid * 4;
            const int r_l = i4 >> 6, bc = i4 & 63;
            const float2 u0 = ld_f2_sc1(pb + i4);
            const float2 u1 = ld_f2_sc1(pb + i4 + 2);
            float* dst = &vsum[((rr ^ 1) * 32 + r_l) * 66 + bc];
            dst[0] = u0.x; dst[1] = u0.y; dst[2] = u1.x; dst[3] = u1.y;
        }
        __syncthreads();   // vsum complete for next step

        Hsh += 524288;
        Hsl += 524288;
    }

    // ---- final: out[b] = sum_p v[p][b] * (sum_e enc(b,11,e) * HL[p][e]) ----
    {
        STAGE_ENC(11);
        __syncthreads();
        const int pg = tid >> 6, bI = tid & 63;   // pg 0..7, 8 p each
        float s = 0.0f;
        #pragma unroll
        for (int i = 0; i < 8; ++i) {
            const int p = pg * 8 + i;
            float L = 0.0f;
            #pragma unroll 16
            for (int e = 0; e < 128; ++e)
                L += enc_s[e * 66 + bI] * HL[p * 128 + e];   // HL row L1-broadcast
            s += vsum[p * 66 + bI] * L;
        }
        red[pg * 66 + bI] = s;
        __syncthreads();
        if (rr == 0 && tid < 64) {
            float acc = 0.0f;
            #pragma unroll
            for (int g = 0; g < 8; ++g)
                acc += red[g * 66 + tid];
            out[b0 + tid] = acc;
        }
    }
    #undef STAGE_ENC
}

extern "C" void kernel_launch(void* const* d_in, const int* in_sizes, int n_in,
                              void* d_out, int out_size, void* d_ws, size_t ws_size,
                              hipStream_t stream) {
    const float* x  = (const float*)d_in[0];
    const float* W1 = (const float*)d_in[1];
    const float* b1 = (const float*)d_in[2];
    const float* W2 = (const float*)d_in[3];
    const float* b2 = (const float*)d_in[4];
    const float* Hf = (const float*)d_in[5];
    const float* Hm = (const float*)d_in[6];
    const float* HL = (const float*)d_in[7];
    float* out = (float*)d_out;
    (void)in_sizes; (void)n_in; (void)out_size; (void)ws_size;

    char* ws = (char*)d_ws;
    __half* encH        = (__half*)(ws + O_ENC);
    unsigned short* HmH = (unsigned short*)(ws + O_HMH);
    unsigned short* HmL = (unsigned short*)(ws + O_HML);
    __half* w1f         = (__half*)(ws + O_W1F);
    __half* w2f         = (__half*)(ws + O_W2F);
    float* vbuf         = (float*)(ws + O_VBUF);

    prep_kernel<<<dim3(1288), dim3(256), 0, stream>>>(W1, W2, Hm, w1f, w2f, HmH, HmL);
    enc_kernel<<<dim3(1536), dim3(256), 0, stream>>>(x, b1, b2, w1f, w2f, encH);
    chain_all<<<dim3(256), dim3(512), 0, stream>>>(HmH, HmL, encH, Hf, HL, vbuf, out);
}

// Round 10
// 414.881 us; speedup vs baseline: 1.0760x; 1.0760x over previous
//
#include <hip/hip_runtime.h>
#include <hip/hip_fp16.h>

// Hankel MPS, round 15: r12 chain (verified 284us = L2-fabric roofline)
//                       + r14 coalesced prep (verified bit-identical).
//
// Round-9 post-mortem (r14 pairs): exchange overhead ~18us/step + 30ms
// replay outlier; pair blocks land on different XCDs under round-robin
// dispatch -> die-crossing handshake on critical path. REVERTED.
//
// Chain roofline evidence: r12 (depth-1) and r13 (depth-2+rotation) both
// pin at 284us = 2MB/CU/step x 10 / ~18TB/s chip L2->CU fabric. Within
// the hi/lo bf16 H format, bytes are minimal (each byte read once/block).
//
// This round: prep 60us -> ~15us (coalesced per-(t,e)-slice conversion);
// everything else is the twice-verified r12 configuration.
//
// ws: encH 25.17M | HmH 10.49M | HmL 10.49M | w1f 64K | w2f 128K  (46.3 MB)

#define B_ALL 8192
#define TT    12
#define B_T   32     // trajectories per block
#define NBLK  256    // 8192 / 32

typedef short bfrag __attribute__((ext_vector_type(8)));      // 8 bf16
typedef _Float16 hfrag __attribute__((ext_vector_type(8)));   // 8 fp16
typedef float ffrag __attribute__((ext_vector_type(16)));     // 32x32 C/D

#define O_ENC   0ULL
#define O_HMH   25165824ULL
#define O_HML   35651584ULL
#define O_W1F   46137344ULL
#define O_W2F   46202880ULL

__device__ __forceinline__ unsigned short bf16_rne(float f) {
    unsigned int u = __builtin_bit_cast(unsigned int, f);
    unsigned int r = (u + 0x7fffu + ((u >> 16) & 1u)) >> 16;
    return (unsigned short)r;
}
__device__ __forceinline__ float bf16_f32(unsigned short h) {
    unsigned int u = ((unsigned int)h) << 16;
    return __builtin_bit_cast(float, u);
}

// ---------------- prep: coalesced H conversion + W frag-order (r14, verified) ----------------
// grid 1288: blocks 0..1279 = one (t,e) H slice each; 1280..1287 = W1/W2.
__global__ __launch_bounds__(256)
void prep_kernel(const float* __restrict__ W1, const float* __restrict__ W2,
                 const float* __restrict__ Hm,
                 __half* __restrict__ w1f, __half* __restrict__ w2f,
                 unsigned short* __restrict__ Hh, unsigned short* __restrict__ Hl)
{
    const int tid = threadIdx.x;
    const int bid = blockIdx.x;
    if (bid < 1280) {
        // one 64p x 64r slice: coalesced read, LDS fragment scatter, coalesced write
        __shared__ unsigned short hs[4096], ls[4096];
        const int t = bid >> 7, e = bid & 127;
        const float* src = Hm + ((size_t)t * 64 * 128 + e) * 64;   // + p*8192 + r
        const int p  = tid >> 2;
        const int rc = (tid & 3) * 16;
        const int fp = (p >> 4) * 512 + ((p >> 3) & 1) * 256 + (p & 7); // p part of f
        #pragma unroll
        for (int k4 = 0; k4 < 4; ++k4) {
            const int r0 = rc + k4 * 4;
            const float4 v4 = *(const float4*)&src[(size_t)p * 8192 + r0];
            const float vv[4] = {v4.x, v4.y, v4.z, v4.w};
            #pragma unroll
            for (int k = 0; k < 4; ++k) {
                const int r = r0 + k;
                const int f = (r >> 5) * 2048 + (r & 31) * 8 + fp;
                const float val = vv[k];
                const unsigned short hi = bf16_rne(val);
                const unsigned short lo = bf16_rne(val - bf16_f32(hi));
                hs[f] = hi;
                ls[f] = lo;
            }
        }
        __syncthreads();
        const size_t q0 = (size_t)t * 524288 + (size_t)e * 4096 + tid * 16;
        *(uint4*)&Hh[q0]     = *(const uint4*)&hs[tid * 16];
        *(uint4*)&Hh[q0 + 8] = *(const uint4*)&hs[tid * 16 + 8];
        *(uint4*)&Hl[q0]     = *(const uint4*)&ls[tid * 16];
        *(uint4*)&Hl[q0 + 8] = *(const uint4*)&ls[tid * 16 + 8];
    } else {
        const int wb = bid - 1280;
        const long long N_W1 = 32768, N_W2 = 65536;
        for (long long idx = wb * 256 + tid; idx < N_W1 + N_W2; idx += 8 * 256) {
            if (idx < N_W1) {
                const int w = (int)idx;
                const int jn = w >> 11, ks = (w >> 9) & 3, half = (w >> 8) & 1;
                const int jl = (w >> 3) & 31, jj = w & 7;
                const int j = jn * 32 + jl, d = ks * 16 + half * 8 + jj;
                w1f[w] = __float2half(W1[j * 64 + d]);
            } else {
                const int w = (int)(idx - N_W1);
                const int en = w >> 14, ks2g = (w >> 9) & 31, half = (w >> 8) & 1;
                const int el = (w >> 3) & 31, jj = w & 7;
                const int e = en * 32 + el, j = ks2g * 16 + half * 8 + jj;
                w2f[w] = __float2half(W2[e * 512 + j]);
            }
        }
    }
}

// ---------------- encoder (unchanged) ----------------
__global__ __launch_bounds__(256)
void enc_kernel(const float* __restrict__ x,
                const float* __restrict__ b1, const float* __restrict__ b2,
                const __half* __restrict__ w1f, const __half* __restrict__ w2f,
                __half* __restrict__ encH)
{
    __shared__ __align__(16) unsigned char smem[17408];
    float* x_s  = (float*)smem;
    __half* h_s = (__half*)smem;

    const int tid   = threadIdx.x;
    const int wv    = tid >> 6;
    const int lane  = tid & 63;
    const int l32   = lane & 31;
    const int half  = lane >> 5;
    const int msub  = wv >> 1;
    const int nhalf = wv & 1;
    const int m0    = blockIdx.x * 64;

    #pragma unroll
    for (int i = 0; i < 4; ++i) {
        const int f4 = i * 256 + tid;
        const int r = f4 >> 4, c4 = (f4 & 15) * 4;
        *(float4*)&x_s[r * 68 + c4] =
            *(const float4*)&x[(long long)(m0 + r) * 64 + c4];
    }
    __syncthreads();

    hfrag xa[4];
    #pragma unroll
    for (int ks = 0; ks < 4; ++ks) {
        const float* src = &x_s[(msub * 32 + l32) * 68 + ks * 16 + half * 8];
        const float4 a = *(const float4*)src;
        const float4 b = *(const float4*)(src + 4);
        hfrag v;
        v[0] = (_Float16)a.x; v[1] = (_Float16)a.y;
        v[2] = (_Float16)a.z; v[3] = (_Float16)a.w;
        v[4] = (_Float16)b.x; v[5] = (_Float16)b.y;
        v[6] = (_Float16)b.z; v[7] = (_Float16)b.w;
        xa[ks] = v;
    }
    __syncthreads();

    ffrag c2[2];
    c2[0] = 0.0f; c2[1] = 0.0f;

    for (int chunk = 0; chunk < 4; ++chunk) {
        ffrag c1[2];
        float b1j[2];
        #pragma unroll
        for (int nf = 0; nf < 2; ++nf) {
            const int jn = chunk * 4 + nhalf * 2 + nf;
            b1j[nf] = b1[jn * 32 + l32];
            ffrag acc = 0.0f;
            #pragma unroll
            for (int ks = 0; ks < 4; ++ks) {
                const hfrag bh = *(const hfrag*)(w1f + (jn * 4 + ks) * 512
                                                 + half * 256 + l32 * 8);
                acc = __builtin_amdgcn_mfma_f32_32x32x16_f16(xa[ks], bh, acc, 0, 0, 0);
            }
            c1[nf] = acc;
        }
        __syncthreads();
        #pragma unroll
        for (int nf = 0; nf < 2; ++nf) {
            #pragma unroll
            for (int i2 = 0; i2 < 16; ++i2) {
                const int m_row = (i2 & 3) + 8 * (i2 >> 2) + 4 * half;
                const float v = fmaxf(c1[nf][i2] + b1j[nf], 0.0f);
                h_s[(msub * 32 + m_row) * 136 + nhalf * 64 + nf * 32 + l32] =
                    __float2half(v);
            }
        }
        __syncthreads();
        #pragma unroll
        for (int ks2 = 0; ks2 < 8; ++ks2) {
            const hfrag a = *(const hfrag*)&h_s[(msub * 32 + l32) * 136
                                                + ks2 * 16 + half * 8];
            const int ks2g = chunk * 8 + ks2;
            #pragma unroll
            for (int ef = 0; ef < 2; ++ef) {
                const int en = nhalf * 2 + ef;
                const hfrag b = *(const hfrag*)(w2f + (en * 32 + ks2g) * 512
                                                + half * 256 + l32 * 8);
                c2[ef] = __builtin_amdgcn_mfma_f32_32x32x16_f16(a, b, c2[ef], 0, 0, 0);
            }
        }
    }

    #pragma unroll
    for (int ef = 0; ef < 2; ++ef) {
        const int e = nhalf * 64 + ef * 32 + l32;
        const float b2e = b2[e];
        #pragma unroll
        for (int i2 = 0; i2 < 16; ++i2) {
            const int m_row = (i2 & 3) + 8 * (i2 >> 2) + 4 * half;
            const int m_g = m0 + msub * 32 + m_row;
            encH[(long long)m_g * 128 + e] =
                __float2half(fmaxf(c2[ef][i2] + b2e, 0.0f));
        }
    }
}

// ---------------- full chain (r12, verified 284us) ----------------
// 256 blocks x 512 thr (1 block/CU). Block owns b0..b0+31. 8 waves:
// eq = wv>>1 (e-quarter, 32 e), rh = wv&1 (r-half). v lives in LDS across
// all steps. e-loop software-pipelined: prefetch e+1 frags before e's MFMAs.
//
// LDS map (60480 B):
//   vsum  @ 0      : [64][33] f32                  = 8448
//   enc_s @ 8448   : [128][33] f32 (one timestep)  = 16896
//   scr   @ 25344  : 6x4 float4 rows, stride 66    = 25312   (chain)
//   hl_s  @ 25344  : [64][129] f32                 = 33024   (final, scr dead)
//   red   @ 58368  : [16][33] f32                  = 2112    (final)
__global__ __launch_bounds__(512, 1)
void chain_all(const unsigned short* __restrict__ HmH,
               const unsigned short* __restrict__ HmL,
               const __half* __restrict__ encH,
               const float* __restrict__ Hf,
               const float* __restrict__ HL,
               float* __restrict__ out)
{
    __shared__ __align__(16) unsigned char smem[60480];
    float* vsum  = (float*)smem;
    float* enc_s = (float*)(smem + 8448);
    float* scr   = (float*)(smem + 25344);
    float* hl_s  = (float*)(smem + 25344);
    float* red   = (float*)(smem + 58368);

    const int tid  = threadIdx.x;
    const int b0   = blockIdx.x * B_T;
    const int lane = tid & 63;
    const int wv   = tid >> 6;
    const int l32  = lane & 31;
    const int half = lane >> 5;
    const int eq   = wv >> 1;      // 0..3  (e-quarter)
    const int rh   = wv & 1;       // 0..1  (r-half)

    // enc staging: [128 e][32 b] f32 for one timestep (all 512 threads)
    const int sbL = tid >> 4;            // 0..31 (b-local)
    const int seo = (tid & 15) * 8;      // 0..120 (e-offset)
    #define STAGE_ENC(T)                                                      \
    {                                                                         \
        const __half* er_ = encH + ((size_t)(b0 + sbL) * 12 + (T)) * 128 + seo;\
        uint4 u = *(const uint4*)er_;                                         \
        const __half* hp_ = (const __half*)&u;                                \
        _Pragma("unroll")                                                     \
        for (int j = 0; j < 8; ++j)                                           \
            enc_s[(seo + j) * 33 + sbL] = __half2float(hp_[j]);               \
    }

    // ---- init: v0[p][b] = sum_e enc(b,0,e) * Hf[e][p] ----
    {
        STAGE_ENC(0);
        __syncthreads();
        const int bI = tid & 31, pg = tid >> 5;   // pg 0..15
        const int p0 = pg * 4;
        float a0 = 0, a1 = 0, a2 = 0, a3 = 0;
        for (int e = 0; e < 128; ++e) {
            const float ev = enc_s[e * 33 + bI];
            const float4 h = *(const float4*)&Hf[e * 64 + p0];  // half-wave-uniform
            a0 += ev * h.x; a1 += ev * h.y; a2 += ev * h.z; a3 += ev * h.w;
        }
        vsum[(p0 + 0) * 33 + bI] = a0;
        vsum[(p0 + 1) * 33 + bI] = a1;
        vsum[(p0 + 2) * 33 + bI] = a2;
        vsum[(p0 + 3) * 33 + bI] = a3;
        __syncthreads();
    }

    // ---- chain: 10 steps, all in-block ----
    const unsigned short* Hsh = HmH;
    const unsigned short* Hsl = HmL;
    // per-lane fragment offset within an e-slice (ushorts):
    // fo(s) = rh*2048 + s*512 + half*256 + l32*8
    const int lanoff = rh * 2048 + half * 256 + l32 * 8;

    #pragma unroll 1
    for (int t = 1; t <= 10; ++t) {
        STAGE_ENC(t);

        // B-frags: v hi/lo split from vsum (stable since last sync)
        bfrag vbh[4], vbl[4];
        #pragma unroll
        for (int s = 0; s < 4; ++s) {
            const int p0 = s * 16 + half * 8;
            bfrag hb, lb;
            #pragma unroll
            for (int j = 0; j < 8; ++j) {
                const float f = vsum[(p0 + j) * 33 + l32];
                const unsigned short hi = bf16_rne(f);
                const unsigned short lo = bf16_rne(f - bf16_f32(hi));
                hb[j] = (short)hi;
                lb[j] = (short)lo;
            }
            vbh[s] = hb;
            vbl[s] = lb;
        }
        __syncthreads();   // enc_s staged; vsum reads complete

        // e-loop: this wave's 32-e quarter, software-pipelined (prefetch e+1)
        const unsigned short* hp = Hsh + (size_t)(eq * 32) * 4096 + lanoff;
        const unsigned short* lp = Hsl + (size_t)(eq * 32) * 4096 + lanoff;
        bfrag cah[4], cal[4];
        #pragma unroll
        for (int s = 0; s < 4; ++s) {
            cah[s] = *(const bfrag*)(hp + s * 512);
            cal[s] = *(const bfrag*)(lp + s * 512);
        }
        ffrag z = 0.0f;
        ffrag vn = 0.0f;
        #pragma unroll 2
        for (int e = 0; e < 32; ++e) {
            hp += 4096; lp += 4096;
            // prefetch next e (last iter reads <=8KB past slice: allocated ws)
            bfrag nah[4], nal[4];
            #pragma unroll
            for (int s = 0; s < 4; ++s) {
                nah[s] = *(const bfrag*)(hp + s * 512);
                nal[s] = *(const bfrag*)(lp + s * 512);
            }
            const float ev = enc_s[(eq * 32 + e) * 33 + l32];
            ffrag w = z;
            #pragma unroll
            for (int s = 0; s < 4; ++s) {
                w = __builtin_amdgcn_mfma_f32_32x32x16_bf16(cah[s], vbh[s], w, 0, 0, 0);
                w = __builtin_amdgcn_mfma_f32_32x32x16_bf16(cah[s], vbl[s], w, 0, 0, 0);
                w = __builtin_amdgcn_mfma_f32_32x32x16_bf16(cal[s], vbh[s], w, 0, 0, 0);
            }
            vn += w * ev;
            #pragma unroll
            for (int s = 0; s < 4; ++s) { cah[s] = nah[s]; cal[s] = nal[s]; }
        }
        __syncthreads();   // e-loop LDS reads done; scr region free

        // cross-eq combine in LDS (stride 66 float4)
        float4* sc4 = (float4*)scr;
        if (eq != 0) {
            const int slot = (eq - 1) * 2 + rh;
            #pragma unroll
            for (int q = 0; q < 4; ++q) {
                float4 f4 = {vn[q * 4 + 0], vn[q * 4 + 1],
                             vn[q * 4 + 2], vn[q * 4 + 3]};
                sc4[(slot * 4 + q) * 66 + lane] = f4;
            }
        }
        __syncthreads();
        if (eq == 0) {
            #pragma unroll
            for (int g = 1; g < 4; ++g) {
                const int slot = (g - 1) * 2 + rh;
                #pragma unroll
                for (int q = 0; q < 4; ++q) {
                    const float4 f4 = sc4[(slot * 4 + q) * 66 + lane];
                    vn[q * 4 + 0] += f4.x; vn[q * 4 + 1] += f4.y;
                    vn[q * 4 + 2] += f4.z; vn[q * 4 + 3] += f4.w;
                }
            }
            #pragma unroll
            for (int i = 0; i < 16; ++i) {
                const int r = rh * 32 + (i & 3) + 8 * (i >> 2) + 4 * half;
                vsum[r * 33 + l32] = vn[i];
            }
        }
        __syncthreads();   // vsum ready for next step

        Hsh += 524288;
        Hsl += 524288;
    }

    // ---- final: out[b] = sum_p v[p][b] * (sum_e enc(b,11,e) * HL[p][e]) ----
    {
        STAGE_ENC(11);
        #pragma unroll
        for (int i = 0; i < 16; ++i) {
            const int idx = i * 512 + tid;       // 8192 floats of HL [p][e]
            hl_s[(idx >> 7) * 129 + (idx & 127)] = HL[idx];
        }
        __syncthreads();
        const int bI = tid & 31, pg = tid >> 5;
        const int p0 = pg * 4;
        float s = 0.0f;
        #pragma unroll
        for (int i = 0; i < 4; ++i) {
            float L = 0.0f;
            #pragma unroll 16
            for (int e = 0; e < 128; ++e)
                L += enc_s[e * 33 + bI] * hl_s[(p0 + i) * 129 + e];
            s += vsum[(p0 + i) * 33 + bI] * L;
        }
        red[pg * 33 + bI] = s;
        __syncthreads();
        if (tid < 32) {
            float acc = 0.0f;
            #pragma unroll
            for (int g = 0; g < 16; ++g)
                acc += red[g * 33 + tid];
            out[b0 + tid] = acc;
        }
    }
    #undef STAGE_ENC
}

extern "C" void kernel_launch(void* const* d_in, const int* in_sizes, int n_in,
                              void* d_out, int out_size, void* d_ws, size_t ws_size,
                              hipStream_t stream) {
    const float* x  = (const float*)d_in[0];
    const float* W1 = (const float*)d_in[1];
    const float* b1 = (const float*)d_in[2];
    const float* W2 = (const float*)d_in[3];
    const float* b2 = (const float*)d_in[4];
    const float* Hf = (const float*)d_in[5];
    const float* Hm = (const float*)d_in[6];
    const float* HL = (const float*)d_in[7];
    float* out = (float*)d_out;
    (void)in_sizes; (void)n_in; (void)out_size; (void)ws_size;

    char* ws = (char*)d_ws;
    __half* encH        = (__half*)(ws + O_ENC);
    unsigned short* HmH = (unsigned short*)(ws + O_HMH);
    unsigned short* HmL = (unsigned short*)(ws + O_HML);
    __half* w1f         = (__half*)(ws + O_W1F);
    __half* w2f         = (__half*)(ws + O_W2F);

    prep_kernel<<<dim3(1288), dim3(256), 0, stream>>>(W1, W2, Hm, w1f, w2f, HmH, HmL);
    enc_kernel<<<dim3(1536), dim3(256), 0, stream>>>(x, b1, b2, w1f, w2f, encH);
    chain_all<<<dim3(NBLK), dim3(512), 0, stream>>>(HmH, HmL, encH, Hf, HL, out);
}